// Round 7
// baseline (222.216 us; speedup 1.0000x reference)
//
#include <hip/hip_runtime.h>
#include <hip/hip_bf16.h>

// MultiHeadSelfAttention: B=2 S=2048 D=1024 H=16 DK=64. fp32 I/O, bf16 internals.
// [cvt x+W fused] -> [QKV gemm (Q pre-scaled by 0.125*log2e, V transposed)] ->
// [flash attn: S^T=K*Q^T so P C-layout feeds PV MFMA directly (k-padded frags,
// no P LDS round-trip), 64q/2-wave blocks, dbuf K/V, exp2+additive mask bias,
// l via ones-MFMA] -> [out-proj 64x128 tiles].
// ws (bf16 elems): xb/ctx[0], Q[4M], K[8M], Vt[12M], Wb[16M..20M] => 40 MB.

#define DEV __device__ __forceinline__

typedef __bf16 bf16_t;
typedef __bf16 bf16x4 __attribute__((ext_vector_type(4)));
typedef __bf16 bf16x8 __attribute__((ext_vector_type(8)));
typedef float f32x4 __attribute__((ext_vector_type(4)));

constexpr int Ss = 2048, Dd = 1024, Hh = 16, DKk = 64;
constexpr float QSCALE = 0.125f * 1.4426950408889634f;  // fold into Q: exp2 domain

DEV void gload_lds16(const void* g, void* l) {
  __builtin_amdgcn_global_load_lds(
      (__attribute__((address_space(1))) void*)(g),
      (__attribute__((address_space(3))) void*)(l), 16, 0, 0);
}

DEV bf16_t f2b(float v) { return (bf16_t)v; }

DEV float fast_exp2(float x) {
#if __has_builtin(__builtin_amdgcn_exp2f)
  return __builtin_amdgcn_exp2f(x);
#else
  return exp2f(x);
#endif
}

// 16 fp32 -> bf16 (32B out)
DEV void cvt16_core(const float* src, bf16_t* dst) {
  const float4* s4 = (const float4*)src;
  float4 a = s4[0], b = s4[1], c = s4[2], d = s4[3];
  bf16x8 lo = {f2b(a.x), f2b(a.y), f2b(a.z), f2b(a.w), f2b(b.x), f2b(b.y), f2b(b.z), f2b(b.w)};
  bf16x8 hi = {f2b(c.x), f2b(c.y), f2b(c.z), f2b(c.w), f2b(d.x), f2b(d.y), f2b(d.z), f2b(d.w)};
  *(bf16x8*)dst = lo;
  *(bf16x8*)(dst + 8) = hi;
}

__global__ __launch_bounds__(256) void cvt16(const float* __restrict__ x,
                                             bf16_t* __restrict__ xb) {
  size_t i = ((size_t)blockIdx.x * 256 + threadIdx.x) * 16;
  cvt16_core(x + i, xb + i);
}

// fused: x (4M) -> xb; Wq/Wk/Wv/Wo (1M each) -> Wb. grid 2048x256.
__global__ __launch_bounds__(256) void cvt_all(
    const float* __restrict__ x,
    const float* __restrict__ wq, const float* __restrict__ wk,
    const float* __restrict__ wv, const float* __restrict__ wo,
    bf16_t* __restrict__ xb, bf16_t* __restrict__ Wb) {
  size_t i = ((size_t)blockIdx.x * 256 + threadIdx.x) * 16;
  const size_t XN = (size_t)4 << 20;
  if (i < XN) {
    cvt16_core(x + i, xb + i);
  } else {
    size_t j = i - XN;
    int z = (int)(j >> 20);
    size_t o = j & (((size_t)1 << 20) - 1);
    const float* s = (z == 0) ? wq : ((z == 1) ? wk : ((z == 2) ? wv : wo));
    cvt16_core(s + o, Wb + j);
  }
}

// ---------------------------------------------------------------------------
// QKV GEMM: C = xb @ W^T + b. A bf16 gload; W bf16 gload (WB16) or fp32 cvt.
// z=0 Q*QSCALE [B*H,S,DK]; z=1 K [B*H,S,DK]; z=2 Vt [B*H,DK,S] (8B stores).
// ---------------------------------------------------------------------------
template <bool WB16>
__global__ __launch_bounds__(256) void gemm_qkv(
    const bf16_t* __restrict__ A,
    const float* __restrict__ W0, const float* __restrict__ W1, const float* __restrict__ W2,
    const bf16_t* __restrict__ Wb,
    const float* __restrict__ b0, const float* __restrict__ b1, const float* __restrict__ b2,
    bf16_t* __restrict__ o0, bf16_t* __restrict__ o1, bf16_t* __restrict__ o2) {
  const int z = blockIdx.z;
  const float* Wf = (z == 0) ? W0 : ((z == 1) ? W1 : W2);
  const bf16_t* Wbf = Wb + (size_t)z * (1u << 20);
  const float* bias = (z == 0) ? b0 : ((z == 1) ? b1 : b2);
  bf16_t* out = (z == 0) ? o0 : ((z == 1) ? o1 : o2);
  const float oscale = (z == 0) ? QSCALE : 1.0f;

  __shared__ __align__(16) bf16_t As[128 * 32];
  __shared__ __align__(16) bf16_t Ws[128 * 32];

  const int tid = threadIdx.x;
  const int lane = tid & 63, w = tid >> 6;
  const int quad = lane >> 4, c = lane & 15;
  const int wm = w >> 1, wn = w & 1;
  const int m0 = blockIdx.y * 128, n0 = blockIdx.x * 128;
  const int trow = tid >> 1, tcol = (tid & 1) * 16;
  const int srow = lane >> 2, scol = (lane & 3) * 8;

  const f32x4 vzero = {0.f, 0.f, 0.f, 0.f};
  f32x4 acc[4][4];
  for (int i = 0; i < 4; i++)
    for (int j = 0; j < 4; j++) acc[i][j] = vzero;

  for (int k0 = 0; k0 < 1024; k0 += 32) {
    for (int r = 0; r < 2; r++) {
      int row = r * 64 + w * 16;  // wave-uniform LDS base
      gload_lds16(&A[(size_t)(m0 + row + srow) * 1024 + k0 + scol], &As[row * 32]);
      if (WB16)
        gload_lds16(&Wbf[(size_t)(n0 + row + srow) * 1024 + k0 + scol], &Ws[row * 32]);
    }
    if (!WB16)
      cvt16_core(&Wf[(size_t)(n0 + trow) * 1024 + k0 + tcol], &Ws[trow * 32 + tcol]);
    __syncthreads();

    bf16x8 af[4], bfr[4];
    for (int i = 0; i < 4; i++)
      af[i] = *(const bf16x8*)&As[(wm * 64 + i * 16 + c) * 32 + quad * 8];
    for (int j = 0; j < 4; j++)
      bfr[j] = *(const bf16x8*)&Ws[(wn * 64 + j * 16 + c) * 32 + quad * 8];
    for (int i = 0; i < 4; i++)
      for (int j = 0; j < 4; j++)
        acc[i][j] = __builtin_amdgcn_mfma_f32_16x16x32_bf16(af[i], bfr[j], acc[i][j], 0, 0, 0);
    __syncthreads();
  }

  for (int j = 0; j < 4; j++) {
    int n = n0 + wn * 64 + j * 16 + c;
    float bv = bias[n];
    for (int i = 0; i < 4; i++) {
      int mbase = m0 + wm * 64 + i * 16 + quad * 4;
      int b_ = mbase >> 11, s_ = mbase & 2047;
      int h_ = n >> 6, dk_ = n & 63;
      if (z < 2) {
        for (int r = 0; r < 4; r++)
          out[((size_t)(b_ * Hh + h_) * Ss + (s_ + r)) * DKk + dk_] =
              f2b((acc[i][j][r] + bv) * oscale);
      } else {
        bf16x4 pk;
        for (int r = 0; r < 4; r++) pk[r] = f2b(acc[i][j][r] + bv);
        *(bf16x4*)&out[((size_t)(b_ * Hh + h_) * DKk + dk_) * Ss + s_] = pk;
      }
    }
  }
}

// ---------------------------------------------------------------------------
// Flash attention. Grid (S/64, B*H), 128 thr = 2 waves; wave owns 32 q (2 mi).
// S^T = K*Q^T so score C-layout [key=quad*4+r][q=c] is directly the A-frag of
// a k-padded 16x16x32 PV MFMA (slots j<4 = keys quad*4+j, j>=4 zero). V B-frag
// via 8B ds_read_b64 from swizzled Vts (same k mapping). No P LDS round-trip.
// Double-buffered K/V staging; mask as additive -1e9 bias; exp2 (Q pre-scaled).
// ---------------------------------------------------------------------------
__global__ __launch_bounds__(128) void attn_fwd(
    const bf16_t* __restrict__ Q, const bf16_t* __restrict__ K,
    const bf16_t* __restrict__ Vt, const int* __restrict__ mask,
    bf16_t* __restrict__ ctx) {
  __shared__ __align__(16) bf16_t Ks[2][64 * 64];
  __shared__ __align__(16) bf16_t Vts[2][64 * 64];

  const int tid = threadIdx.x, lane = tid & 63, w = tid >> 6;
  const int quad = lane >> 4, c = lane & 15;
  const int c7 = c & 7;
  const int bh = blockIdx.y, b_ = bh >> 4, h_ = bh & 15;
  const int q0 = blockIdx.x * 64 + w * 32;
  const size_t head = (size_t)bh * Ss * DKk;
  const int* maskb = mask + b_ * Ss;

  const int sr = lane >> 3;        // staging row within 8
  const int gc = (lane & 7) ^ sr;  // swizzled source chunk

  // prefetch tile 0 into buf 0 (4 rounds x 8 rows per wave; 2 waves cover 64)
  for (int r = 0; r < 4; r++) {
    int row = w * 32 + r * 8;  // wave-uniform
    gload_lds16(&K[head + (size_t)(row + sr) * 64 + gc * 8], &Ks[0][row * 64]);
    gload_lds16(&Vt[head + (size_t)(row + sr) * Ss + gc * 8], &Vts[0][row * 64]);
  }

  // Q B-fragments: B[k=quad*8+j][n=c] = Q[q0+mi*16+c][ks*32+quad*8+j]
  bf16x8 qf[2][2];
  for (int mi = 0; mi < 2; mi++)
    for (int ks = 0; ks < 2; ks++)
      qf[mi][ks] = *(const bf16x8*)&Q[head + (size_t)(q0 + mi * 16 + c) * DKk + ks * 32 + quad * 8];

  // mask prefetch for tile 0: key = ni*16 + quad*4 + r
  int4 mk4[4];
  for (int ni = 0; ni < 4; ni++) mk4[ni] = *(const int4*)&maskb[ni * 16 + quad * 4];

  const bf16_t oneb = f2b(1.0f), zb = f2b(0.0f);
  const bf16x8 ones = {oneb, oneb, oneb, oneb, zb, zb, zb, zb};  // k-padded

  const f32x4 vzero = {0.f, 0.f, 0.f, 0.f};
  f32x4 o[2][4];
  for (int mi = 0; mi < 2; mi++)
    for (int t = 0; t < 4; t++) o[mi][t] = vzero;
  f32x4 ol[2] = {vzero, vzero};

  constexpr int NT = Ss / 64;
  for (int kt = 0; kt < NT; kt++) {
    const int cur = kt & 1;
    __syncthreads();  // tile kt landed; buf cur free of previous readers

    if (kt + 1 < NT) {
      int nxt = cur ^ 1;
      for (int r = 0; r < 4; r++) {
        int row = w * 32 + r * 8;
        gload_lds16(&K[head + (size_t)((kt + 1) * 64 + row + sr) * 64 + gc * 8],
                    &Ks[nxt][row * 64]);
        gload_lds16(&Vt[head + (size_t)(row + sr) * Ss + (kt + 1) * 64 + gc * 8],
                    &Vts[nxt][row * 64]);
      }
    }
    int4 mk4n[4];
    if (kt + 1 < NT)
      for (int ni = 0; ni < 4; ni++)
        mk4n[ni] = *(const int4*)&maskb[(kt + 1) * 64 + ni * 16 + quad * 4];

    // S^T = K*Q^T: sc[mi][ni] C-layout [key=ni*16+quad*4+r][q=q0+mi*16+c]
    f32x4 sc[2][4];
    for (int mi = 0; mi < 2; mi++)
      for (int ni = 0; ni < 4; ni++) sc[mi][ni] = vzero;
    for (int ks = 0; ks < 2; ks++) {
      int pc = ((ks * 4 + quad) ^ c7) * 8;
      for (int ni = 0; ni < 4; ni++) {
        bf16x8 kf = *(const bf16x8*)&Ks[cur][(ni * 16 + c) * 64 + pc];
        sc[0][ni] = __builtin_amdgcn_mfma_f32_16x16x32_bf16(kf, qf[0][ks], sc[0][ni], 0, 0, 0);
        sc[1][ni] = __builtin_amdgcn_mfma_f32_16x16x32_bf16(kf, qf[1][ks], sc[1][ni], 0, 0, 0);
      }
    }

    // additive mask bias (exp2 domain), shared across mi
    f32x4 mb[4];
    for (int ni = 0; ni < 4; ni++) {
      mb[ni][0] = mk4[ni].x ? 0.f : -1e9f;
      mb[ni][1] = mk4[ni].y ? 0.f : -1e9f;
      mb[ni][2] = mk4[ni].z ? 0.f : -1e9f;
      mb[ni][3] = mk4[ni].w ? 0.f : -1e9f;
    }

    // PV + rowsum, per 16-key chunk ni: P chunk as k-padded A-frag (registers)
    for (int ni = 0; ni < 4; ni++) {
      bf16x8 a0, a1;
      for (int r = 0; r < 4; r++) {
        a0[r] = f2b(fast_exp2(sc[0][ni][r] + mb[ni][r]));
        a1[r] = f2b(fast_exp2(sc[1][ni][r] + mb[ni][r]));
        a0[4 + r] = zb;
        a1[4 + r] = zb;
      }
      const int vcol = (((ni * 2 + (quad >> 1)) ^ c7) * 8) + (quad & 1) * 4;
      for (int t = 0; t < 4; t++) {
        bf16x4 v4 = *(const bf16x4*)&Vts[cur][(t * 16 + c) * 64 + vcol];
        bf16x8 vf = {v4[0], v4[1], v4[2], v4[3], zb, zb, zb, zb};
        o[0][t] = __builtin_amdgcn_mfma_f32_16x16x32_bf16(a0, vf, o[0][t], 0, 0, 0);
        o[1][t] = __builtin_amdgcn_mfma_f32_16x16x32_bf16(a1, vf, o[1][t], 0, 0, 0);
      }
      ol[0] = __builtin_amdgcn_mfma_f32_16x16x32_bf16(a0, ones, ol[0], 0, 0, 0);
      ol[1] = __builtin_amdgcn_mfma_f32_16x16x32_bf16(a1, ones, ol[1], 0, 0, 0);
    }

    for (int ni = 0; ni < 4; ni++) mk4[ni] = mk4n[ni];
  }

  // O C-layout: row=q=quad*4+r, col=dk=t*16+c ; l same rows
  for (int mi = 0; mi < 2; mi++) {
    float inv[4];
    for (int r = 0; r < 4; r++) inv[r] = 1.0f / ol[mi][r];
    for (int t = 0; t < 4; t++)
      for (int r = 0; r < 4; r++) {
        int s_ = q0 + mi * 16 + quad * 4 + r;
        ctx[((size_t)(b_ * Ss + s_)) * Dd + h_ * 64 + t * 16 + c] =
            f2b(o[mi][t][r] * inv[r]);
      }
  }
}

// ---------------------------------------------------------------------------
// Out-proj: out = ctx @ Wo^T + bo (fp32 out). 64x128 tiles, grid (8,64).
// ---------------------------------------------------------------------------
template <bool WB16>
__global__ __launch_bounds__(256) void gemm_out(
    const bf16_t* __restrict__ A, const float* __restrict__ Wf,
    const bf16_t* __restrict__ Wb, const float* __restrict__ bias,
    float* __restrict__ out) {
  __shared__ __align__(16) bf16_t As[64 * 32];
  __shared__ __align__(16) bf16_t Ws[128 * 32];

  const int tid = threadIdx.x;
  const int lane = tid & 63, w = tid >> 6;
  const int quad = lane >> 4, c = lane & 15;
  const int wm = w >> 1, wn = w & 1;
  const int m0 = blockIdx.y * 64, n0 = blockIdx.x * 128;
  const int trow = tid >> 1, tcol = (tid & 1) * 16;
  const int srow = lane >> 2, scol = (lane & 3) * 8;

  const f32x4 vzero = {0.f, 0.f, 0.f, 0.f};
  f32x4 acc[2][4];
  for (int i = 0; i < 2; i++)
    for (int j = 0; j < 4; j++) acc[i][j] = vzero;

  for (int k0 = 0; k0 < 1024; k0 += 32) {
    gload_lds16(&A[(size_t)(m0 + w * 16 + srow) * 1024 + k0 + scol], &As[(w * 16) * 32]);
    if (WB16) {
      for (int r = 0; r < 2; r++) {
        int row = r * 64 + w * 16;
        gload_lds16(&Wb[(size_t)(n0 + row + srow) * 1024 + k0 + scol], &Ws[row * 32]);
      }
    } else {
      cvt16_core(&Wf[(size_t)(n0 + trow) * 1024 + k0 + tcol], &Ws[trow * 32 + tcol]);
    }
    __syncthreads();

    bf16x8 af[2], bfr[4];
    for (int i = 0; i < 2; i++)
      af[i] = *(const bf16x8*)&As[(wm * 32 + i * 16 + c) * 32 + quad * 8];
    for (int j = 0; j < 4; j++)
      bfr[j] = *(const bf16x8*)&Ws[(wn * 64 + j * 16 + c) * 32 + quad * 8];
    for (int i = 0; i < 2; i++)
      for (int j = 0; j < 4; j++)
        acc[i][j] = __builtin_amdgcn_mfma_f32_16x16x32_bf16(af[i], bfr[j], acc[i][j], 0, 0, 0);
    __syncthreads();
  }

  for (int j = 0; j < 4; j++) {
    int n = n0 + wn * 64 + j * 16 + c;
    float bv = bias[n];
    for (int i = 0; i < 2; i++) {
      int mbase = m0 + wm * 32 + i * 16 + quad * 4;
      for (int r = 0; r < 4; r++)
        out[(size_t)(mbase + r) * 1024 + n] = acc[i][j][r] + bv;
    }
  }
}

// ---------------------------------------------------------------------------
extern "C" void kernel_launch(void* const* d_in, const int* in_sizes, int n_in,
                              void* d_out, int out_size, void* d_ws, size_t ws_size,
                              hipStream_t stream) {
  const float* x  = (const float*)d_in[0];
  const int* mask = (const int*)d_in[1];
  const float* Wq = (const float*)d_in[2];
  const float* bq = (const float*)d_in[3];
  const float* Wk = (const float*)d_in[4];
  const float* bk = (const float*)d_in[5];
  const float* Wv = (const float*)d_in[6];
  const float* bv = (const float*)d_in[7];
  const float* Wo = (const float*)d_in[8];
  const float* bo = (const float*)d_in[9];
  float* out = (float*)d_out;

  bf16_t* ws = (bf16_t*)d_ws;
  const size_t QKV_ELEMS = (size_t)2 * Hh * Ss * DKk;  // 4M
  bf16_t* xb  = ws;          // reused as ctx after gemm_qkv is done with it
  bf16_t* Qb  = ws + QKV_ELEMS;
  bf16_t* Kb  = ws + 2 * QKV_ELEMS;
  bf16_t* Vt  = ws + 3 * QKV_ELEMS;
  bf16_t* Wb  = ws + 4 * QKV_ELEMS;  // 4M elems (4 matrices x 1M)
  bf16_t* ctx = xb;

  const bool wb16 = ws_size >= (size_t)40 * 1024 * 1024;

  if (wb16) {
    cvt_all<<<dim3(2048), 256, 0, stream>>>(x, Wq, Wk, Wv, Wo, xb, Wb);
    gemm_qkv<true><<<dim3(8, 32, 3), 256, 0, stream>>>(
        xb, Wq, Wk, Wv, Wb, bq, bk, bv, Qb, Kb, Vt);
  } else {
    cvt16<<<dim3(1024), 256, 0, stream>>>(x, xb);
    gemm_qkv<false><<<dim3(8, 32, 3), 256, 0, stream>>>(
        xb, Wq, Wk, Wv, ws /*unused*/, bq, bk, bv, Qb, Kb, Vt);
  }
  attn_fwd<<<dim3(Ss / 64, 2 * Hh), 128, 0, stream>>>(Qb, Kb, Vt, mask, ctx);
  if (wb16)
    gemm_out<true><<<dim3(8, 64), 256, 0, stream>>>(ctx, Wo, Wb + 3 * (1u << 20), bo, out);
  else
    gemm_out<false><<<dim3(8, 64), 256, 0, stream>>>(ctx, Wo, ws /*unused*/, bo, out);
}